// Round 13
// baseline (48.040 us; speedup 1.0000x reference)
//
#include <hip/hip_runtime.h>
#include <hip/hip_fp16.h>

// Problem constants (match reference)
#define NRAYS 1048576
#define NV 32
#define ND 32
#define NF 6
#define NK 13  // 2F+1

typedef _Float16 h2 __attribute__((ext_vector_type(2)));
typedef float f4 __attribute__((ext_vector_type(4)));

__device__ __forceinline__ float fdot2acc(h2 a, h2 b, float c) {
#if __has_builtin(__builtin_amdgcn_fdot2)
    return __builtin_amdgcn_fdot2(a, b, c, false);
#else
    return c + (float)a.x * (float)b.x + (float)a.y * (float)b.y;
#endif
}

__device__ __forceinline__ h2 pack2(float a, float b) {
#if __has_builtin(__builtin_amdgcn_cvt_pkrtz)
    return __builtin_bit_cast(h2, __builtin_amdgcn_cvt_pkrtz(a, b));
#else
    h2 r; r.x = (_Float16)a; r.y = (_Float16)b; return r;
#endif
}

__device__ __forceinline__ float hwsin(float rev) {
#if __has_builtin(__builtin_amdgcn_sinf)
    return __builtin_amdgcn_sinf(rev);
#else
    return __sinf(6.28318530717958647692f * rev);
#endif
}
__device__ __forceinline__ float hwcos(float rev) {
#if __has_builtin(__builtin_amdgcn_cosf)
    return __builtin_amdgcn_cosf(rev);
#else
    return __cosf(6.28318530717958647692f * rev);
#endif
}

__device__ __forceinline__ void make_basis(float t, h2 bp[7]) {
    float sv[NF], cv[NF];
    sv[0] = hwsin(0.5f * t);
    cv[0] = hwcos(0.5f * t);
#pragma unroll
    for (int j = 1; j < NF; ++j) {
        float sj = sv[j - 1], cj = cv[j - 1];
        sv[j] = 2.f * sj * cj;
        cv[j] = fmaf(-2.f * sj, sj, 1.f);
    }
    bp[0] = pack2(1.0f, sv[0]);
    bp[1] = pack2(sv[1], sv[2]);
    bp[2] = pack2(sv[3], sv[4]);
    bp[3] = pack2(sv[5], cv[0]);
    bp[4] = pack2(cv[1], cv[2]);
    bp[5] = pack2(cv[3], cv[4]);
    bp[6] = pack2(cv[5], 0.0f);  // pad half must be 0
}

// ---------------------------------------------------------------------------
// Kernel A: pack f32 weights [V][D][K] into a f16 image in d_ws (28 KB; this
// LIVES IN L1 during the main kernel). Plain layout, dword idx =
// v*224 + i*32 + q*4 + e  ->  d = 4q+e, halves (k=2i, 2i+1); pad k=13 = 0.
__global__ void pack_weights_kernel(const float* __restrict__ weights,
                                    unsigned* __restrict__ wpack)
{
    int j = blockIdx.x * 256 + threadIdx.x;  // 0 .. 7167 (dwords)
    if (j >= NV * 7 * 32) return;
    int v = j / 224;
    int r = j - v * 224;
    int i = r >> 5;          // k-pair 0..6
    int c = r & 31;
    int q = c >> 2;          // d-quad
    int e = c & 3;
    int d = 4 * q + e;
    float w0 = weights[v * (ND * NK) + d * NK + 2 * i];
    float w1 = (2 * i + 1 < NK) ? weights[v * (ND * NK) + d * NK + 2 * i + 1] : 0.f;
    wpack[j] = __builtin_bit_cast(unsigned, pack2(w0, w1));
}

// ---------------------------------------------------------------------------
// Main kernel — NO LDS. Weights come from the 28 KB global image (L1-resident:
// R9 shadows proved the loop hits the store roofline when weight access stays
// off the LDS pipe; ds_read+store in one loop was the measured pathology).
// 8 threads per ray: thread q owns d = 4q..4q+3. Weight regs double-buffered,
// t/vid prefetched 2 ahead, plain (cached) 16B stores.
__global__ __launch_bounds__(256, 4) void VideoEmbedding_kernel(
    const float* __restrict__ times,
    const int* __restrict__ vids,
    const unsigned* __restrict__ wpack,
    float* __restrict__ out)
{
    const int tid = threadIdx.x;
    const int q = tid & 7;
    const int gs = (gridDim.x * 256) >> 3;  // 65536 ray-slots
    int ray = ((blockIdx.x * 256) + tid) >> 3;

    const uint4* __restrict__ wsrc = reinterpret_cast<const uint4*>(wpack);
    // uint4 index: v*56 + i*8 + q

    // t/vid ring: current, +1, +2
    float t0, t1, t2;
    int v0, v1, v2;
    t0 = times[ray]; v0 = vids[ray];
    int rr = min(ray + gs, NRAYS - 1);
    t1 = times[rr]; v1 = vids[rr];
    rr = min(ray + 2 * gs, NRAYS - 1);
    t2 = times[rr]; v2 = vids[rr];

    uint4 wA[7], wB[7];
    {
        const int b = v0 * 56 + q;
#pragma unroll
        for (int i = 0; i < 7; ++i)
            wA[i] = wsrc[b + i * 8];
    }

#define STAGE(WCUR, WNEXT)                                                    \
    {                                                                         \
        /* global prefetch for ray+3 */                                       \
        rr = min(ray + 3 * gs, NRAYS - 1);                                    \
        const float t3 = times[rr];                                           \
        const int v3 = vids[rr];                                              \
        /* issue weight loads for ray+1 into WNEXT (L1 hits) */               \
        {                                                                     \
            const int nb = v1 * 56 + q;                                       \
            _Pragma("unroll")                                                 \
            for (int i = 0; i < 7; ++i)                                       \
                WNEXT[i] = wsrc[nb + i * 8];                                  \
        }                                                                     \
        /* compute + store current ray from WCUR */                           \
        {                                                                     \
            h2 bp[7];                                                         \
            make_basis(t0, bp);                                               \
            float a0 = 0.f, a1 = 0.f, a2 = 0.f, a3 = 0.f;                     \
            _Pragma("unroll")                                                 \
            for (int i = 0; i < 7; ++i) {                                     \
                a0 = fdot2acc(__builtin_bit_cast(h2, WCUR[i].x), bp[i], a0);  \
                a1 = fdot2acc(__builtin_bit_cast(h2, WCUR[i].y), bp[i], a1);  \
                a2 = fdot2acc(__builtin_bit_cast(h2, WCUR[i].z), bp[i], a2);  \
                a3 = fdot2acc(__builtin_bit_cast(h2, WCUR[i].w), bp[i], a3);  \
            }                                                                 \
            f4 res;                                                           \
            res.x = a0; res.y = a1; res.z = a2; res.w = a3;                   \
            reinterpret_cast<f4*>(out)[(size_t)ray * 8 + q] = res;            \
        }                                                                     \
        ray += gs;                                                            \
        if (ray >= NRAYS) break;                                              \
        t0 = t1; t1 = t2; t2 = t3;                                            \
        v0 = v1; v1 = v2; v2 = v3;                                            \
    }

    while (true) {
        STAGE(wA, wB)   // even iteration: compute from wA, fill wB
        STAGE(wB, wA)   // odd iteration: compute from wB, fill wA
    }
#undef STAGE
}

extern "C" void kernel_launch(void* const* d_in, const int* in_sizes, int n_in,
                              void* d_out, int out_size, void* d_ws, size_t ws_size,
                              hipStream_t stream) {
    const float* times = (const float*)d_in[0];
    const int* vids = (const int*)d_in[1];
    const float* weights = (const float*)d_in[2];
    float* out = (float*)d_out;
    unsigned* wpack = (unsigned*)d_ws;

    hipLaunchKernelGGL(pack_weights_kernel, dim3(28), dim3(256), 0, stream,
                       weights, wpack);
    // 2048 blocks, no LDS; 16 iterations/slot exactly.
    hipLaunchKernelGGL(VideoEmbedding_kernel, dim3(2048), dim3(256), 0, stream,
                       times, vids, wpack, out);
}

// Round 14
// 36.754 us; speedup vs baseline: 1.3071x; 1.3071x over previous
//
#include <hip/hip_runtime.h>
#include <hip/hip_fp16.h>

// Problem constants (match reference)
#define NRAYS 1048576
#define NV 32
#define ND 32
#define NF 6
#define NK 13   // 2F+1
#define RPB 1024      // rays per block
#define NTILE_MAX 96  // max 16-row tiles per block: 1024/16 + 32

typedef _Float16 h2 __attribute__((ext_vector_type(2)));
typedef _Float16 h8 __attribute__((ext_vector_type(8)));
typedef float f4 __attribute__((ext_vector_type(4)));

__device__ __forceinline__ h2 pack2(float a, float b) {
#if __has_builtin(__builtin_amdgcn_cvt_pkrtz)
    return __builtin_bit_cast(h2, __builtin_amdgcn_cvt_pkrtz(a, b));
#else
    h2 r; r.x = (_Float16)a; r.y = (_Float16)b; return r;
#endif
}
__device__ __forceinline__ float hwsin(float rev) {
#if __has_builtin(__builtin_amdgcn_sinf)
    return __builtin_amdgcn_sinf(rev);
#else
    return __sinf(6.28318530717958647692f * rev);
#endif
}
__device__ __forceinline__ float hwcos(float rev) {
#if __has_builtin(__builtin_amdgcn_cosf)
    return __builtin_amdgcn_cosf(rev);
#else
    return __cosf(6.28318530717958647692f * rev);
#endif
}

// ---------------------------------------------------------------------------
// Kernel A: pre-format weights into MFMA B-fragments (f16), 64 KB image.
// For mfma_f32_16x16x32_f16: lane l holds B[k=(l>>4)*8+j][col=l&15], j=0..7.
// dword idx = ((v*2+dhalf)*64 + lane)*4 + e  -> halves j=2e,2e+1; k>=13 -> 0.
__global__ void pack_weights_kernel(const float* __restrict__ weights,
                                    unsigned* __restrict__ wfrag)
{
    int idx = blockIdx.x * 256 + threadIdx.x;  // 0 .. 16383
    if (idx >= 16384) return;
    int v = idx >> 9;
    int r = idx & 511;
    int dhalf = r >> 8;
    int r2 = r & 255;
    int lane = r2 >> 2;
    int e = r2 & 3;
    int d = dhalf * 16 + (lane & 15);
    int k0 = (lane >> 4) * 8 + 2 * e;
    const float* wp = weights + v * (ND * NK) + d * NK;
    float w0 = (k0 < NK) ? wp[k0] : 0.f;
    float w1 = (k0 + 1 < NK) ? wp[k0 + 1] : 0.f;
    wfrag[idx] = __builtin_bit_cast(unsigned, pack2(w0, w1));
}

// ---------------------------------------------------------------------------
// Main kernel. Block owns 1024 contiguous rays.
// Phase 1: counting-sort rays by vid (LDS); each thread computes its 4 rays'
//   f16 basis ONCE and writes the 16-half row to the sorted slot.
// Phase 2: per 16-row vid-uniform tile: 1 ds_read_b128 A-frag + 2 L1 uint4
//   B-frags + 2 MFMA (d 0-15, 16-31) + 8 store-masked dword stores.
// Tiles overhang into the next bucket; overhang rows are store-masked (those
// rays are recomputed in their own vid's tile), so no padding is needed.
__global__ __launch_bounds__(256, 4) void VideoEmbedding_kernel(
    const float* __restrict__ times,
    const int* __restrict__ vids,
    const uint4* __restrict__ wfrag,
    float* __restrict__ out)
{
    __shared__ __align__(16) _Float16 s_bt[(RPB + 16) * 16];  // 33280 B
    __shared__ unsigned short s_meta[RPB];                    //  2048 B
    __shared__ int hist[NV];
    __shared__ unsigned ttab[NTILE_MAX];
    __shared__ int s_nT;

    const int tid = threadIdx.x;
    const int rbase = blockIdx.x * RPB;

    if (tid < NV) hist[tid] = 0;
    __syncthreads();

    float t[4];
    int v[4];
#pragma unroll
    for (int it = 0; it < 4; ++it) {
        int lid = it * 256 + tid;
        t[it] = times[rbase + lid];
        v[it] = vids[rbase + lid];
        atomicAdd(&hist[v[it]], 1);
    }
    __syncthreads();

    if (tid < NV) {
        int c = hist[tid];
        int sum = c;
#pragma unroll
        for (int off = 1; off < NV; off <<= 1) {
            int n = __shfl_up(sum, off, NV);
            if (tid >= off) sum += n;
        }
        int excl = sum - c;
        hist[tid] = excl;  // becomes the scatter cursor
        // tile table: ntile = ceil(c/16); entry = v<<22 | end<<11 | rowstart
        int nt = (c + 15) >> 4;
        int tsum = nt;
#pragma unroll
        for (int off = 1; off < NV; off <<= 1) {
            int n = __shfl_up(tsum, off, NV);
            if (tid >= off) tsum += n;
        }
        int texcl = tsum - nt;
        if (tid == NV - 1) s_nT = tsum;
        unsigned endv = (unsigned)(excl + c);
        for (int s = 0; s < nt; ++s)
            ttab[texcl + s] =
                ((unsigned)tid << 22) | (endv << 11) | (unsigned)(excl + 16 * s);
        // zero the 16 overhang basis rows (slots RPB..RPB+15)
        uint4 zz; zz.x = zz.y = zz.z = zz.w = 0u;
        *reinterpret_cast<uint4*>(&s_bt[RPB * 16 + tid * 8]) = zz;
    }
    __syncthreads();

    // scatter: sorted slot, basis row (16 f16 halves: [1,s0..s5,c0..c5,0,0,0])
#pragma unroll
    for (int it = 0; it < 4; ++it) {
        int slot = atomicAdd(&hist[v[it]], 1);
        s_meta[slot] = (unsigned short)(it * 256 + tid);
        float sv[NF], cv[NF];
        sv[0] = hwsin(0.5f * t[it]);
        cv[0] = hwcos(0.5f * t[it]);
#pragma unroll
        for (int j = 1; j < NF; ++j) {
            float sj = sv[j - 1], cj = cv[j - 1];
            sv[j] = 2.f * sj * cj;
            cv[j] = fmaf(-2.f * sj, sj, 1.f);
        }
        uint4 lo, hi;
        lo.x = __builtin_bit_cast(unsigned, pack2(1.0f, sv[0]));
        lo.y = __builtin_bit_cast(unsigned, pack2(sv[1], sv[2]));
        lo.z = __builtin_bit_cast(unsigned, pack2(sv[3], sv[4]));
        lo.w = __builtin_bit_cast(unsigned, pack2(sv[5], cv[0]));
        hi.x = __builtin_bit_cast(unsigned, pack2(cv[1], cv[2]));
        hi.y = __builtin_bit_cast(unsigned, pack2(cv[3], cv[4]));
        hi.z = __builtin_bit_cast(unsigned, pack2(cv[5], 0.0f));
        hi.w = 0u;
        uint4* bt = reinterpret_cast<uint4*>(&s_bt[slot * 16]);
        bt[0] = lo;
        bt[1] = hi;
    }
    __syncthreads();

    // phase 2: waves process tiles independently
    const int wid = tid >> 6;
    const int lane = tid & 63;
    const int lrow = lane & 15;
    const int lkc = lane >> 4;
    const int T = s_nT;

    for (int tt = wid; tt < T; tt += 4) {
        const unsigned e = ttab[tt];
        const int rowstart = (int)(e & 0x7FFu);
        const int rend = (int)((e >> 11) & 0x7FFu);
        const int vv = (int)(e >> 22);

        // A-fragment: lane holds basis[row=rowstart+lrow][k=lkc*8 .. +7]
        h8 a = *reinterpret_cast<const h8*>(
            &s_bt[(rowstart + lrow) * 16 + lkc * 8]);
        // B-fragments for d 0-15 and 16-31 (L1-resident 64 KB image)
        uint4 b0u = wfrag[(vv * 2 + 0) * 64 + lane];
        uint4 b1u = wfrag[(vv * 2 + 1) * 64 + lane];

        f4 z = {0.f, 0.f, 0.f, 0.f};
        f4 c0 = __builtin_amdgcn_mfma_f32_16x16x32_f16(
            a, __builtin_bit_cast(h8, b0u), z, 0, 0, 0);
        f4 c1 = __builtin_amdgcn_mfma_f32_16x16x32_f16(
            a, __builtin_bit_cast(h8, b1u), z, 0, 0, 0);

        // C layout: col = lane&15 (=d within half), row = (lane>>4)*4 + j
#pragma unroll
        for (int j = 0; j < 4; ++j) {
            const int srow = rowstart + lkc * 4 + j;
            if (srow < rend) {
                const int lidx = s_meta[srow];
                float* o = out + (size_t)(rbase + lidx) * 32 + lrow;
                o[0] = c0[j];
                o[16] = c1[j];
            }
        }
    }
}

extern "C" void kernel_launch(void* const* d_in, const int* in_sizes, int n_in,
                              void* d_out, int out_size, void* d_ws, size_t ws_size,
                              hipStream_t stream) {
    const float* times = (const float*)d_in[0];
    const int* vids = (const int*)d_in[1];
    const float* weights = (const float*)d_in[2];
    float* out = (float*)d_out;
    unsigned* wfrag = (unsigned*)d_ws;

    hipLaunchKernelGGL(pack_weights_kernel, dim3(64), dim3(256), 0, stream,
                       weights, wfrag);
    // 1024 blocks x 1024 rays; 4 blocks/CU (35.5 KB LDS), one generation.
    hipLaunchKernelGGL(VideoEmbedding_kernel, dim3(1024), dim3(256), 0, stream,
                       times, vids, (const uint4*)wfrag, out);
}